// Round 6
// baseline (457.368 us; speedup 1.0000x reference)
//
#include <hip/hip_runtime.h>
#include <cfloat>
#include <climits>
#include <math.h>

// Problem constants
#define BB 2048
#define NN 50000
#define DD 128
#define KK 20

// K1 geometry: 24 slices x 2112 padded entries (66 tiles of 32)
#define NSLICE 24
#define SLE 2112
#define NTILE 66
#define NPAD 50688        // NSLICE*SLE, pads 50000..50687 (benign scores)
#define CAND 288          // NSLICE * 12 stored per row per task

// out layout (floats): vals_cos, ind_cos, labels_rot, vals_euc, ind_euc, labels_trans
#define O_VC 0
#define O_IC 40960
#define O_LR 81920
#define O_VE 122880
#define O_IE 163840
#define O_LT 204800

// ws layout (bytes): Bbf 25.95MB | bq2 203KB | candU 2.36MB = 28.51MB (< 28.81MB proven)
#define WS_BBF   0
#define WS_BQ2   25952256
#define WS_CAND  26155008

typedef short v8s __attribute__((ext_vector_type(8)));
typedef float v16f __attribute__((ext_vector_type(16)));

union U4V8 { uint4 u; v8s v; };

__device__ __forceinline__ unsigned int bf16rne(float f) {
    unsigned int x = __float_as_uint(f);
    return (x + 0x7FFFu + ((x >> 16) & 1u)) >> 16;
}
// monotone fp32 -> u32 total order
__device__ __forceinline__ unsigned int sortkey(float s) {
    unsigned int b = __float_as_uint(s);
    unsigned int m = ((unsigned int)((int)b >> 31)) >> 1;
    return b ^ (0x80000000u | m);
}

// ---------------- K0: padded bf16 book (cos: b, euc: 2b) + packed -bq ----------------
__global__ __launch_bounds__(256) void k_cvt2(const float* __restrict__ bR,
                                              const float* __restrict__ bT,
                                              unsigned int* __restrict__ Bbf,
                                              unsigned int* __restrict__ bq2)
{
    const int t = threadIdx.x;
    const int job = (blockIdx.x * 256 + t) >> 5;     // 0 .. 2*NPAD-1
    const int l = t & 31;
    const int task = job >= NPAD;
    const int e = job - task * NPAD;

    uint2 o = make_uint2(0u, 0u);
    float sq = 0.f;
    if (e < NN) {
        const float* src = (task ? bT : bR) + (size_t)e * DD + l * 4;
        float4 v = *reinterpret_cast<const float4*>(src);
        sq = v.x * v.x + v.y * v.y + v.z * v.z + v.w * v.w;   // from ORIGINAL b
        const float sc = task ? 2.f : 1.f;
        o.x = bf16rne(v.x * sc) | (bf16rne(v.y * sc) << 16);
        o.y = bf16rne(v.z * sc) | (bf16rne(v.w * sc) << 16);
    }
    reinterpret_cast<uint2*>(Bbf)[(size_t)job * 32 + l] = o;

    if (task) {
        #pragma unroll
        for (int m = 1; m < 32; m <<= 1) sq += __shfl_xor(sq, m, 64);
        if (l == 0) {
            unsigned int pk;
            if (e < NN) {
                unsigned int hi = bf16rne(sq);
                float fhi = __uint_as_float(hi << 16);
                unsigned int lo = bf16rne(sq - fhi);
                pk = (hi ^ 0x8000u) | ((lo ^ 0x8000u) << 16);   // (-bq_hi, -bq_lo)
            } else {
                pk = 0x0000FF7Fu;   // -3.39e38 -> pad euc score ~ -3.4e38
            }
            bq2[e] = pk;
        }
    }
}

// ---------------- K1: MFMA scoring + branchless bitonic per-lane top-8 ---------------
// One wave per (slice, rowgroup32, task). A = book entries, B = z rows.
// C layout: z-row = lane&31; entry m = (r&3)+8*(r>>2)+4*(lane>>5).
// Keys: hi16 = sortkey(score)>>16 slot, low16 = code (tile<<5 | r<<1 | h).

#define CEK(i,j) { unsigned int lo_ = min(K[i], K[j]); K[j] = max(K[i], K[j]); K[i] = lo_; }
#define SORT8A CEK(0,1) CEK(2,3) CEK(4,5) CEK(6,7) CEK(0,2) CEK(1,3) CEK(4,6) CEK(5,7) \
               CEK(1,2) CEK(5,6) CEK(0,4) CEK(1,5) CEK(2,6) CEK(3,7) CEK(2,4) CEK(3,5) \
               CEK(1,2) CEK(3,4) CEK(5,6)
#define SORT8B CEK(8,9) CEK(10,11) CEK(12,13) CEK(14,15) CEK(8,10) CEK(9,11) CEK(12,14) CEK(13,15) \
               CEK(9,10) CEK(13,14) CEK(8,12) CEK(9,13) CEK(10,14) CEK(11,15) CEK(10,12) CEK(11,13) \
               CEK(9,10) CEK(11,12) CEK(13,14)
#define CEA(A,i,j) { unsigned int lo_ = min(A[i], A[j]); A[j] = max(A[i], A[j]); A[i] = lo_; }
#define BMERGE(A) CEA(A,0,4) CEA(A,1,5) CEA(A,2,6) CEA(A,3,7) \
                  CEA(A,0,2) CEA(A,1,3) CEA(A,4,6) CEA(A,5,7) \
                  CEA(A,0,1) CEA(A,2,3) CEA(A,4,5) CEA(A,6,7)

#define LOADT(bb, bqp, tile_)                                                          \
{                                                                                      \
    const unsigned int* ep_ = bp + (size_t)(sbase + (tile_) * 32 + col) * 64 + h * 4;  \
    _Pragma("unroll")                                                                  \
    for (int q = 0; q < 8; q++) bb[q] = *reinterpret_cast<const uint4*>(ep_ + q * 8);  \
    if (task) bqp = bq2[sbase + (tile_) * 32 + col];                                   \
}

#define PROCESS(bb, bqp, tile_)                                                        \
{                                                                                      \
    v16f acc = {0.f,0.f,0.f,0.f,0.f,0.f,0.f,0.f,0.f,0.f,0.f,0.f,0.f,0.f,0.f,0.f};     \
    _Pragma("unroll")                                                                  \
    for (int q = 0; q < 8; q++) {                                                      \
        U4V8 a_; a_.u = bb[q];                                                         \
        acc = __builtin_amdgcn_mfma_f32_32x32x16_bf16(a_.v, zf[q], acc, 0, 0, 0);      \
    }                                                                                  \
    if (task) {                                                                        \
        U4V8 a_; a_.u = make_uint4(h == 0 ? (bqp) : 0u, 0u, 0u, 0u);                   \
        acc = __builtin_amdgcn_mfma_f32_32x32x16_bf16(a_.v, zf[8], acc, 0, 0, 0);      \
    }                                                                                  \
    const unsigned int tc = (unsigned int)(tile_) << 5;                                \
    unsigned int K[16];                                                                \
    _Pragma("unroll")                                                                  \
    for (int r = 0; r < 16; r++)                                                       \
        K[r] = (sortkey(acc[r]) & 0xFFFF0000u) | tc | (unsigned int)((r << 1) | h);    \
    SORT8A; SORT8B;                                                                    \
    unsigned int T[8];                                                                 \
    _Pragma("unroll")                                                                  \
    for (int i = 0; i < 8; i++) T[i] = max(K[i], K[15 - i]);                           \
    BMERGE(T);                                                                         \
    unsigned int V[8];                                                                 \
    _Pragma("unroll")                                                                  \
    for (int i = 0; i < 8; i++) V[i] = max(T[i], R[7 - i]);                            \
    BMERGE(V);                                                                         \
    _Pragma("unroll")                                                                  \
    for (int i = 0; i < 8; i++) R[i] = V[i];                                           \
}

__global__ __launch_bounds__(64, 3) void k1_sel(
    const float* __restrict__ zR, const float* __restrict__ zT,
    const unsigned int* __restrict__ Bbf,
    const unsigned int* __restrict__ bq2,
    unsigned int* __restrict__ candU32)
{
    const int slice = blockIdx.x;       // 0..23 (slice%8 -> XCD; 3.2MB/XCD book set)
    const int rg    = blockIdx.y;       // 0..63
    const int task  = blockIdx.z;
    const int lane  = threadIdx.x;
    const int col   = lane & 31;
    const int h     = lane >> 5;
    const unsigned int sbase = slice * SLE;

    // persistent z-frags (B operand): row = rg*32+col, k = 16q+8h..+8
    const float* zp = (task ? zT : zR) + (size_t)(rg * 32 + col) * DD;
    v8s zf[9];
    #pragma unroll
    for (int q = 0; q < 8; q++) {
        float4 u0 = *reinterpret_cast<const float4*>(zp + q * 16 + h * 8);
        float4 u1 = *reinterpret_cast<const float4*>(zp + q * 16 + h * 8 + 4);
        U4V8 c;
        c.u.x = bf16rne(u0.x) | (bf16rne(u0.y) << 16);
        c.u.y = bf16rne(u0.z) | (bf16rne(u0.w) << 16);
        c.u.z = bf16rne(u1.x) | (bf16rne(u1.y) << 16);
        c.u.w = bf16rne(u1.z) | (bf16rne(u1.w) << 16);
        zf[q] = c.v;
    }
    {   // 9th K-step: k=128,129 -> 1.0,1.0 on h=0; zeros on h=1
        U4V8 c; c.u = make_uint4(h == 0 ? 0x3F803F80u : 0u, 0u, 0u, 0u);
        zf[8] = c.v;
    }

    const unsigned int* bp = Bbf + (size_t)task * NPAD * 64;

    unsigned int R[8];
    #pragma unroll
    for (int i = 0; i < 8; i++) R[i] = 0u;   // real keys always > 0; filled by tile 0

    uint4 b0[8], b1[8];
    unsigned int bq0 = 0u, bq1 = 0u;
    LOADT(b0, bq0, 0)
    for (int tp = 0; tp < NTILE; tp += 2) {
        LOADT(b1, bq1, tp + 1)
        PROCESS(b0, bq0, tp)
        if (tp + 2 < NTILE) LOADT(b0, bq0, tp + 2)
        PROCESS(b1, bq1, tp + 1)
    }

    // writeout: top-12 of the lane-pair union = own[4..7] + 2 cross-maxes per lane
    unsigned int P[8];
    #pragma unroll
    for (int i = 0; i < 8; i++) P[i] = (unsigned int)__shfl_xor((int)R[i], 32, 64);
    unsigned int st[6];
    st[0] = R[4]; st[1] = R[5]; st[2] = R[6]; st[3] = R[7];
    st[4] = max(R[0], P[3]); st[5] = max(R[1], P[2]);

    unsigned int ns[6];
    #pragma unroll
    for (int i = 0; i < 6; i++) {
        unsigned int c = st[i] & 0xFFFFu;
        unsigned int n = sbase + ((c >> 5) << 5) + ((c >> 1) & 3u)
                       + (((c >> 3) & 3u) << 3) + ((c & 1u) << 2);
        ns[i] = min(n, 49999u);   // pad entries (>=50000) -> real entry (dup-safe in K2)
    }
    const int row = rg * 32 + col;
    const size_t cb = ((size_t)(task * BB + row) * NSLICE + slice) * 6 + (size_t)h * 3;
    candU32[cb + 0] = ns[0] | (ns[1] << 16);
    candU32[cb + 1] = ns[2] | (ns[3] << 16);
    candU32[cb + 2] = ns[4] | (ns[5] << 16);
}

// ---------------- K2: exact final ranking + gather (verified logic, CAND=288) --------
__device__ __forceinline__ float np_euc_score(int n, const float* __restrict__ Bk,
                                              const float* zrow) {
    const float* brow = Bk + (size_t)n * DD;
    float L[4], r[8], q[8];
    #pragma unroll
    for (int u = 0; u < 4; u++) L[u] = 0.f;
    #pragma unroll
    for (int u = 0; u < 8; u++) { r[u] = 0.f; q[u] = 0.f; }
    #pragma unroll
    for (int c4 = 0; c4 < 32; c4++) {
        float4 b4 = *reinterpret_cast<const float4*>(brow + c4 * 4);
        float4 z4 = *reinterpret_cast<const float4*>(&zrow[c4 * 4]);
        const int m8 = (c4 & 1) * 4;
        L[0] = __fadd_rn(L[0], __fmul_rn(z4.x, b4.x));
        L[1] = __fadd_rn(L[1], __fmul_rn(z4.y, b4.y));
        L[2] = __fadd_rn(L[2], __fmul_rn(z4.z, b4.z));
        L[3] = __fadd_rn(L[3], __fmul_rn(z4.w, b4.w));
        r[m8 + 0] = __fadd_rn(r[m8 + 0], __fmul_rn(b4.x, b4.x));
        r[m8 + 1] = __fadd_rn(r[m8 + 1], __fmul_rn(b4.y, b4.y));
        r[m8 + 2] = __fadd_rn(r[m8 + 2], __fmul_rn(b4.z, b4.z));
        r[m8 + 3] = __fadd_rn(r[m8 + 3], __fmul_rn(b4.w, b4.w));
        q[m8 + 0] = __fadd_rn(q[m8 + 0], __fmul_rn(z4.x, z4.x));
        q[m8 + 1] = __fadd_rn(q[m8 + 1], __fmul_rn(z4.y, z4.y));
        q[m8 + 2] = __fadd_rn(q[m8 + 2], __fmul_rn(z4.z, z4.z));
        q[m8 + 3] = __fadd_rn(q[m8 + 3], __fmul_rn(z4.w, z4.w));
    }
    const float dot = __fadd_rn(__fadd_rn(L[0], L[2]), __fadd_rn(L[1], L[3]));
    const float bqv = __fadd_rn(__fadd_rn(__fadd_rn(r[0], r[1]), __fadd_rn(r[2], r[3])),
                                __fadd_rn(__fadd_rn(r[4], r[5]), __fadd_rn(r[6], r[7])));
    const float zqv = __fadd_rn(__fadd_rn(__fadd_rn(q[0], q[1]), __fadd_rn(q[2], q[3])),
                                __fadd_rn(__fadd_rn(q[4], q[5]), __fadd_rn(q[6], q[7])));
    return __fsub_rn(__fsub_rn(__fmul_rn(2.0f, dot), zqv), bqv);
}

__global__ __launch_bounds__(256) void k2_final(
    const float* __restrict__ Zr, const float* __restrict__ Zt,
    const float* __restrict__ Br, const float* __restrict__ Bt,
    const float* __restrict__ rotB, const float* __restrict__ transB,
    const unsigned int* __restrict__ candU32,
    float* __restrict__ out)
{
    const int row = blockIdx.x;
    const int task = blockIdx.y;
    const int t = threadIdx.x;
    const float* __restrict__ Z  = task ? Zt : Zr;
    const float* __restrict__ Bk = task ? Bt : Br;

    __shared__ __align__(16) float zrow[DD];
    __shared__ int sel[CAND];
    __shared__ double dotp[CAND * 8];
    __shared__ double sval[KK];
    __shared__ int sidx[KK];
    __shared__ float sv[CAND];

    if (t < DD) zrow[t] = Z[(size_t)row * DD + t];
    if (t < 144) {   // 144 u32 = 288 u16 candidates
        unsigned int w = candU32[(size_t)(task * BB + row) * 144 + t];
        sel[2 * t] = (int)(w & 0xFFFFu);
        sel[2 * t + 1] = (int)(w >> 16);
    }
    __syncthreads();

    if (task == 0) {
        // ---- cos: exact fp64 rescore + top-20 ----
        #pragma unroll
        for (int it = 0; it < 9; it++) {
            int idx = t + it * 256;          // < 2304 = CAND*8 exactly
            int cnd = idx >> 3, part = idx & 7;
            int n = sel[cnd];
            const float* brow = Bk + (size_t)n * DD + part * 16;
            double dp = 0.0;
            #pragma unroll
            for (int q = 0; q < 4; q++) {
                float4 b4 = *reinterpret_cast<const float4*>(brow + q * 4);
                const int k = part * 16 + q * 4;
                dp += (double)zrow[k + 0] * (double)b4.x + (double)zrow[k + 1] * (double)b4.y
                    + (double)zrow[k + 2] * (double)b4.z + (double)zrow[k + 3] * (double)b4.w;
            }
            dotp[idx] = dp;
        }
        __syncthreads();

        if (t < 64) {
            double zq = (double)zrow[t] * (double)zrow[t]
                      + (double)zrow[t + 64] * (double)zrow[t + 64];
            #pragma unroll
            for (int m = 1; m < 64; m <<= 1) zq += __shfl_xor(zq, m, 64);

            double s[5]; int ix[5];
            #pragma unroll
            for (int j = 0; j < 4; j++) {
                const int c = t + 64 * j;
                double dot = 0.0;
                #pragma unroll
                for (int p = 0; p < 8; p++) dot += dotp[c * 8 + p];
                s[j] = dot; ix[j] = sel[c];
            }
            if (t < 32) {
                const int c = 256 + t;
                double dot = 0.0;
                #pragma unroll
                for (int p = 0; p < 8; p++) dot += dotp[c * 8 + p];
                s[4] = dot; ix[4] = sel[c];
            } else { s[4] = -DBL_MAX; ix[4] = INT_MAX; }

            for (int rd = 0; rd < KK; rd++) {
                double bs = s[0]; int bn = ix[0];
                #pragma unroll
                for (int j = 1; j < 5; j++)
                    if (s[j] > bs || (s[j] == bs && ix[j] < bn)) { bs = s[j]; bn = ix[j]; }
                #pragma unroll
                for (int m = 1; m < 64; m <<= 1) {
                    double os = __shfl_xor(bs, m, 64);
                    int on = __shfl_xor(bn, m, 64);
                    if (os > bs || (os == bs && on < bn)) { bs = os; bn = on; }
                }
                #pragma unroll
                for (int j = 0; j < 5; j++) if (ix[j] == bn) s[j] = -DBL_MAX;  // pop all dups
                if (t == 0) { sval[rd] = bs; sidx[rd] = bn; }
            }
            if (t == 0) dotp[0] = zq;
        }
        __syncthreads();

        if (t < KK) {
            const double zq = dotp[0];
            const int n = sidx[t];
            const int o = row * KK + t;
            out[O_VC + o] = (float)(sval[t] / sqrt(zq));
            out[O_IC + o] = (float)n;
            out[O_LR + o] = rotB[n];
        }
    } else {
        // ---- euc: bit-exact numpy-fp32 emulation (verified R3/R5) ----
        sv[t] = np_euc_score(sel[t], Bk, zrow);
        if (t < 32) sv[256 + t] = np_euc_score(sel[256 + t], Bk, zrow);
        __syncthreads();

        if (t < 64) {
            float s[5]; int ix[5];
            #pragma unroll
            for (int j = 0; j < 4; j++) { s[j] = sv[t + 64 * j]; ix[j] = sel[t + 64 * j]; }
            if (t < 32) { s[4] = sv[256 + t]; ix[4] = sel[256 + t]; }
            else        { s[4] = -FLT_MAX; ix[4] = INT_MAX; }

            for (int rd = 0; rd < KK; rd++) {
                float bs = s[0]; int bn = ix[0];
                #pragma unroll
                for (int j = 1; j < 5; j++)
                    if (s[j] > bs || (s[j] == bs && ix[j] < bn)) { bs = s[j]; bn = ix[j]; }
                #pragma unroll
                for (int m = 1; m < 64; m <<= 1) {
                    float os = __shfl_xor(bs, m, 64);
                    int on = __shfl_xor(bn, m, 64);
                    if (os > bs || (os == bs && on < bn)) { bs = os; bn = on; }
                }
                #pragma unroll
                for (int j = 0; j < 5; j++) if (ix[j] == bn) s[j] = -FLT_MAX;
                if (t == 0) {
                    const int o = row * KK + rd;
                    out[O_VE + o] = bs;
                    out[O_IE + o] = (float)bn;
                    const int o3 = O_LT + o * 3;
                    out[o3 + 0] = transB[bn * 3 + 0];
                    out[o3 + 1] = transB[bn * 3 + 1];
                    out[o3 + 2] = transB[bn * 3 + 2];
                }
            }
        }
    }
}

// ---------------- launch ------------------------------------------------------------
extern "C" void kernel_launch(void* const* d_in, const int* in_sizes, int n_in,
                              void* d_out, int out_size, void* d_ws, size_t ws_size,
                              hipStream_t stream) {
    const float* zR = (const float*)d_in[0];
    const float* zT = (const float*)d_in[1];
    const float* bR = (const float*)d_in[2];
    const float* bT = (const float*)d_in[3];
    const float* rotB = (const float*)d_in[4];
    const float* transB = (const float*)d_in[5];
    float* out = (float*)d_out;

    char* ws = (char*)d_ws;
    unsigned int* Bbf = (unsigned int*)(ws + WS_BBF);
    unsigned int* bq2 = (unsigned int*)(ws + WS_BQ2);
    unsigned int* candU32 = (unsigned int*)(ws + WS_CAND);

    // 2*NPAD entries * 32 lanes / 256 = 12672 blocks
    k_cvt2<<<12672, 256, 0, stream>>>(bR, bT, Bbf, bq2);
    k1_sel<<<dim3(NSLICE, 64, 2), 64, 0, stream>>>(zR, zT, Bbf, bq2, candU32);
    k2_final<<<dim3(BB, 2), 256, 0, stream>>>(zR, zT, bR, bT, rotB, transB, candU32, out);
}

// Round 7
// 447.112 us; speedup vs baseline: 1.0229x; 1.0229x over previous
//
#include <hip/hip_runtime.h>
#include <cfloat>
#include <climits>
#include <math.h>

// Problem constants
#define BB 2048
#define NN 50000
#define DD 128
#define KK 20

// K1 geometry: 24 slices x 2112 padded entries (66 tiles of 32)
#define NSLICE 24
#define SLE 2112
#define NTILE 66
#define NPAD 50688        // NSLICE*SLE, pads 50000..50687 (benign scores)
#define CAND 288          // NSLICE * 12 stored per row per task

// out layout (floats): vals_cos, ind_cos, labels_rot, vals_euc, ind_euc, labels_trans
#define O_VC 0
#define O_IC 40960
#define O_LR 81920
#define O_VE 122880
#define O_IE 163840
#define O_LT 204800

// ws layout (bytes): Bbf 25.95MB | bq2 203KB | candU 2.36MB = 28.51MB (< 28.81MB proven)
#define WS_BBF   0
#define WS_BQ2   25952256
#define WS_CAND  26155008

typedef short v8s __attribute__((ext_vector_type(8)));
typedef float v16f __attribute__((ext_vector_type(16)));

union U4V8 { uint4 u; v8s v; };

__device__ __forceinline__ unsigned int bf16rne(float f) {
    unsigned int x = __float_as_uint(f);
    return (x + 0x7FFFu + ((x >> 16) & 1u)) >> 16;
}
// monotone fp32 -> u32 total order
__device__ __forceinline__ unsigned int sortkey(float s) {
    unsigned int b = __float_as_uint(s);
    unsigned int m = ((unsigned int)((int)b >> 31)) >> 1;
    return b ^ (0x80000000u | m);
}

// ---------------- K0a: book -> MFMA-fragment-ordered bf16 layout ---------------------
// Layout: [task][tile][q][lane] 16B chunks; lane = col + 32h; chunk = entry(col) bytes
// [q*32+h*16, +16) i.e. k in [16q+8h, +8). Writes are LINEAR (fully coalesced).
__global__ __launch_bounds__(256) void k_cvt(const float* __restrict__ bR,
                                             const float* __restrict__ bT,
                                             uint4* __restrict__ Bbf)
{
    const unsigned int d16 = blockIdx.x * 256 + threadIdx.x;   // < 2*NPAD*16
    const unsigned int col  = d16 & 31;
    const unsigned int h    = (d16 >> 5) & 1;
    const unsigned int q    = (d16 >> 6) & 7;
    const unsigned int tile = (d16 >> 9) % (NPAD / 32);
    const int task = d16 >= (NPAD * 16);
    const unsigned int e = tile * 32 + col;

    uint4 o = make_uint4(0u, 0u, 0u, 0u);
    if (e < NN) {
        const float* src = (task ? bT : bR) + (size_t)e * DD + q * 16 + h * 8;
        float4 f0 = *reinterpret_cast<const float4*>(src);
        float4 f1 = *reinterpret_cast<const float4*>(src + 4);
        const float sc = task ? 2.f : 1.f;
        o.x = bf16rne(f0.x * sc) | (bf16rne(f0.y * sc) << 16);
        o.y = bf16rne(f0.z * sc) | (bf16rne(f0.w * sc) << 16);
        o.z = bf16rne(f1.x * sc) | (bf16rne(f1.y * sc) << 16);
        o.w = bf16rne(f1.z * sc) | (bf16rne(f1.w * sc) << 16);
    }
    Bbf[d16] = o;
}

// ---------------- K0b: packed -bq (hi/lo bf16) incl. pad sentinel --------------------
__global__ __launch_bounds__(256) void k_bq(const float* __restrict__ bT,
                                            unsigned int* __restrict__ bq2)
{
    const int gid = blockIdx.x * 256 + threadIdx.x;
    const int e = gid >> 5;
    const int l = threadIdx.x & 31;
    if (e < NN) {
        float4 v = *reinterpret_cast<const float4*>(bT + (size_t)e * DD + l * 4);
        float sq = v.x * v.x + v.y * v.y + v.z * v.z + v.w * v.w;
        #pragma unroll
        for (int m = 1; m < 32; m <<= 1) sq += __shfl_xor(sq, m, 64);
        if (l == 0) {
            unsigned int hi = bf16rne(sq);
            float fhi = __uint_as_float(hi << 16);
            unsigned int lo = bf16rne(sq - fhi);
            bq2[e] = (hi ^ 0x8000u) | ((lo ^ 0x8000u) << 16);   // (-bq_hi, -bq_lo)
        }
    } else if (l == 0) {
        bq2[e] = 0x0000FF7Fu;   // pad euc score ~ -3.4e38
    }
}

// ---------------- K1: MFMA scoring + branchless bitonic per-lane top-8 ---------------
// One wave per (slice, rowgroup32, task). A = book entries, B = z rows.
// C layout: z-row = lane&31; entry m = (r&3)+8*(r>>2)+4*(lane>>5).
// Keys: hi16 = sortkey(score)>>16, low16 = code (tile<<5 | r<<1 | h).

#define CEK(i,j) { unsigned int lo_ = min(K[i], K[j]); K[j] = max(K[i], K[j]); K[i] = lo_; }
#define SORT8A CEK(0,1) CEK(2,3) CEK(4,5) CEK(6,7) CEK(0,2) CEK(1,3) CEK(4,6) CEK(5,7) \
               CEK(1,2) CEK(5,6) CEK(0,4) CEK(1,5) CEK(2,6) CEK(3,7) CEK(2,4) CEK(3,5) \
               CEK(1,2) CEK(3,4) CEK(5,6)
#define SORT8B CEK(8,9) CEK(10,11) CEK(12,13) CEK(14,15) CEK(8,10) CEK(9,11) CEK(12,14) CEK(13,15) \
               CEK(9,10) CEK(13,14) CEK(8,12) CEK(9,13) CEK(10,14) CEK(11,15) CEK(10,12) CEK(11,13) \
               CEK(9,10) CEK(11,12) CEK(13,14)
#define CEA(A,i,j) { unsigned int lo_ = min(A[i], A[j]); A[j] = max(A[i], A[j]); A[i] = lo_; }
#define BMERGE(A) CEA(A,0,4) CEA(A,1,5) CEA(A,2,6) CEA(A,3,7) \
                  CEA(A,0,2) CEA(A,1,3) CEA(A,4,6) CEA(A,5,7) \
                  CEA(A,0,1) CEA(A,2,3) CEA(A,4,5) CEA(A,6,7)

// coalesced: per q one 1KB wave-contiguous 16B/lane load
#define LOADT(bb, bqp, tt_)                                                            \
{                                                                                      \
    const unsigned int* tb_ = bp32 + (((size_t)(slice * NTILE + (tt_))) << 11)         \
                            + (lane << 2);                                             \
    _Pragma("unroll")                                                                  \
    for (int q = 0; q < 8; q++)                                                        \
        bb[q] = *reinterpret_cast<const uint4*>(tb_ + (q << 8));                       \
    if (task) bqp = bq2[sbase + (tt_) * 32 + col];                                     \
}

#define PROCESS(bb, bqp, tt_)                                                          \
{                                                                                      \
    v16f acc = {0.f,0.f,0.f,0.f,0.f,0.f,0.f,0.f,0.f,0.f,0.f,0.f,0.f,0.f,0.f,0.f};     \
    _Pragma("unroll")                                                                  \
    for (int q = 0; q < 8; q++) {                                                      \
        U4V8 a_; a_.u = bb[q];                                                         \
        acc = __builtin_amdgcn_mfma_f32_32x32x16_bf16(a_.v, zf[q], acc, 0, 0, 0);      \
    }                                                                                  \
    if (task) {                                                                        \
        U4V8 a_; a_.u = make_uint4(h == 0 ? (bqp) : 0u, 0u, 0u, 0u);                   \
        acc = __builtin_amdgcn_mfma_f32_32x32x16_bf16(a_.v, zf[8], acc, 0, 0, 0);      \
    }                                                                                  \
    const unsigned int tc = (unsigned int)(tt_) << 5;                                  \
    unsigned int K[16];                                                                \
    _Pragma("unroll")                                                                  \
    for (int r = 0; r < 16; r++)                                                       \
        K[r] = (sortkey(acc[r]) & 0xFFFF0000u) | tc | (unsigned int)((r << 1) | h);    \
    SORT8A; SORT8B;                                                                    \
    unsigned int T[8];                                                                 \
    _Pragma("unroll")                                                                  \
    for (int i = 0; i < 8; i++) T[i] = max(K[i], K[15 - i]);                           \
    BMERGE(T);                                                                         \
    unsigned int V[8];                                                                 \
    _Pragma("unroll")                                                                  \
    for (int i = 0; i < 8; i++) V[i] = max(T[i], R[7 - i]);                            \
    BMERGE(V);                                                                         \
    _Pragma("unroll")                                                                  \
    for (int i = 0; i < 8; i++) R[i] = V[i];                                           \
}

// tile-order rotation (de-convoy): wave-private visit order, codes stay absolute
#define TTW(x) (((x) + t0 >= NTILE) ? ((x) + t0 - NTILE) : ((x) + t0))

__global__ __launch_bounds__(64, 4) void k1_sel(
    const float* __restrict__ zR, const float* __restrict__ zT,
    const unsigned int* __restrict__ Bbf,
    const unsigned int* __restrict__ bq2,
    unsigned int* __restrict__ candU32)
{
    const int slice = blockIdx.x;       // 0..23 (slice%8 -> XCD; slice set L2-resident)
    const int rg    = blockIdx.y;       // 0..63
    const int task  = blockIdx.z;
    const int lane  = threadIdx.x;
    const int col   = lane & 31;
    const int h     = lane >> 5;
    const unsigned int sbase = slice * SLE;
    const int t0 = (rg * 7) % NTILE;

    // persistent z-frags (B operand): row = rg*32+col, k = 16q+8h..+8
    const float* zp = (task ? zT : zR) + (size_t)(rg * 32 + col) * DD;
    v8s zf[9];
    #pragma unroll
    for (int q = 0; q < 8; q++) {
        float4 u0 = *reinterpret_cast<const float4*>(zp + q * 16 + h * 8);
        float4 u1 = *reinterpret_cast<const float4*>(zp + q * 16 + h * 8 + 4);
        U4V8 c;
        c.u.x = bf16rne(u0.x) | (bf16rne(u0.y) << 16);
        c.u.y = bf16rne(u0.z) | (bf16rne(u0.w) << 16);
        c.u.z = bf16rne(u1.x) | (bf16rne(u1.y) << 16);
        c.u.w = bf16rne(u1.z) | (bf16rne(u1.w) << 16);
        zf[q] = c.v;
    }
    {   // 9th K-step: k=128,129 -> 1.0,1.0 on h=0; zeros on h=1
        U4V8 c; c.u = make_uint4(h == 0 ? 0x3F803F80u : 0u, 0u, 0u, 0u);
        zf[8] = c.v;
    }

    const unsigned int* bp32 = Bbf + (size_t)task * NPAD * 64;

    unsigned int R[8];
    #pragma unroll
    for (int i = 0; i < 8; i++) R[i] = 0u;   // real keys always > 0

    uint4 b0[8], b1[8];
    unsigned int bq0 = 0u, bq1 = 0u;
    LOADT(b0, bq0, TTW(0))
    for (int tp = 0; tp < NTILE; tp += 2) {
        LOADT(b1, bq1, TTW(tp + 1))
        PROCESS(b0, bq0, TTW(tp))
        if (tp + 2 < NTILE) LOADT(b0, bq0, TTW(tp + 2))
        PROCESS(b1, bq1, TTW(tp + 1))
    }

    // writeout: top-12 of the lane-pair union = own[4..7] + 2 cross-maxes per lane
    unsigned int P[8];
    #pragma unroll
    for (int i = 0; i < 8; i++) P[i] = (unsigned int)__shfl_xor((int)R[i], 32, 64);
    unsigned int st[6];
    st[0] = R[4]; st[1] = R[5]; st[2] = R[6]; st[3] = R[7];
    st[4] = max(R[0], P[3]); st[5] = max(R[1], P[2]);

    unsigned int ns[6];
    #pragma unroll
    for (int i = 0; i < 6; i++) {
        unsigned int c = st[i] & 0xFFFFu;
        unsigned int n = sbase + ((c >> 5) << 5) + ((c >> 1) & 3u)
                       + (((c >> 3) & 3u) << 3) + ((c & 1u) << 2);
        ns[i] = min(n, 49999u);   // pad entries (>=50000) -> real entry (dup-safe in K2)
    }
    const int row = rg * 32 + col;
    const size_t cb = ((size_t)(task * BB + row) * NSLICE + slice) * 6 + (size_t)h * 3;
    candU32[cb + 0] = ns[0] | (ns[1] << 16);
    candU32[cb + 1] = ns[2] | (ns[3] << 16);
    candU32[cb + 2] = ns[4] | (ns[5] << 16);
}

// ---------------- K2: exact final ranking + gather (verified logic, CAND=288) --------
__device__ __forceinline__ float np_euc_score(int n, const float* __restrict__ Bk,
                                              const float* zrow) {
    const float* brow = Bk + (size_t)n * DD;
    float L[4], r[8], q[8];
    #pragma unroll
    for (int u = 0; u < 4; u++) L[u] = 0.f;
    #pragma unroll
    for (int u = 0; u < 8; u++) { r[u] = 0.f; q[u] = 0.f; }
    #pragma unroll
    for (int c4 = 0; c4 < 32; c4++) {
        float4 b4 = *reinterpret_cast<const float4*>(brow + c4 * 4);
        float4 z4 = *reinterpret_cast<const float4*>(&zrow[c4 * 4]);
        const int m8 = (c4 & 1) * 4;
        L[0] = __fadd_rn(L[0], __fmul_rn(z4.x, b4.x));
        L[1] = __fadd_rn(L[1], __fmul_rn(z4.y, b4.y));
        L[2] = __fadd_rn(L[2], __fmul_rn(z4.z, b4.z));
        L[3] = __fadd_rn(L[3], __fmul_rn(z4.w, b4.w));
        r[m8 + 0] = __fadd_rn(r[m8 + 0], __fmul_rn(b4.x, b4.x));
        r[m8 + 1] = __fadd_rn(r[m8 + 1], __fmul_rn(b4.y, b4.y));
        r[m8 + 2] = __fadd_rn(r[m8 + 2], __fmul_rn(b4.z, b4.z));
        r[m8 + 3] = __fadd_rn(r[m8 + 3], __fmul_rn(b4.w, b4.w));
        q[m8 + 0] = __fadd_rn(q[m8 + 0], __fmul_rn(z4.x, z4.x));
        q[m8 + 1] = __fadd_rn(q[m8 + 1], __fmul_rn(z4.y, z4.y));
        q[m8 + 2] = __fadd_rn(q[m8 + 2], __fmul_rn(z4.z, z4.z));
        q[m8 + 3] = __fadd_rn(q[m8 + 3], __fmul_rn(z4.w, z4.w));
    }
    const float dot = __fadd_rn(__fadd_rn(L[0], L[2]), __fadd_rn(L[1], L[3]));
    const float bqv = __fadd_rn(__fadd_rn(__fadd_rn(r[0], r[1]), __fadd_rn(r[2], r[3])),
                                __fadd_rn(__fadd_rn(r[4], r[5]), __fadd_rn(r[6], r[7])));
    const float zqv = __fadd_rn(__fadd_rn(__fadd_rn(q[0], q[1]), __fadd_rn(q[2], q[3])),
                                __fadd_rn(__fadd_rn(q[4], q[5]), __fadd_rn(q[6], q[7])));
    return __fsub_rn(__fsub_rn(__fmul_rn(2.0f, dot), zqv), bqv);
}

__global__ __launch_bounds__(256) void k2_final(
    const float* __restrict__ Zr, const float* __restrict__ Zt,
    const float* __restrict__ Br, const float* __restrict__ Bt,
    const float* __restrict__ rotB, const float* __restrict__ transB,
    const unsigned int* __restrict__ candU32,
    float* __restrict__ out)
{
    const int row = blockIdx.x;
    const int task = blockIdx.y;
    const int t = threadIdx.x;
    const float* __restrict__ Z  = task ? Zt : Zr;
    const float* __restrict__ Bk = task ? Bt : Br;

    __shared__ __align__(16) float zrow[DD];
    __shared__ int sel[CAND];
    __shared__ double dotp[CAND * 8];
    __shared__ double sval[KK];
    __shared__ int sidx[KK];
    __shared__ float sv[CAND];

    if (t < DD) zrow[t] = Z[(size_t)row * DD + t];
    if (t < 144) {   // 144 u32 = 288 u16 candidates
        unsigned int w = candU32[(size_t)(task * BB + row) * 144 + t];
        sel[2 * t] = (int)(w & 0xFFFFu);
        sel[2 * t + 1] = (int)(w >> 16);
    }
    __syncthreads();

    if (task == 0) {
        // ---- cos: exact fp64 rescore + top-20 ----
        #pragma unroll
        for (int it = 0; it < 9; it++) {
            int idx = t + it * 256;          // < 2304 = CAND*8 exactly
            int cnd = idx >> 3, part = idx & 7;
            int n = sel[cnd];
            const float* brow = Bk + (size_t)n * DD + part * 16;
            double dp = 0.0;
            #pragma unroll
            for (int q = 0; q < 4; q++) {
                float4 b4 = *reinterpret_cast<const float4*>(brow + q * 4);
                const int k = part * 16 + q * 4;
                dp += (double)zrow[k + 0] * (double)b4.x + (double)zrow[k + 1] * (double)b4.y
                    + (double)zrow[k + 2] * (double)b4.z + (double)zrow[k + 3] * (double)b4.w;
            }
            dotp[idx] = dp;
        }
        __syncthreads();

        if (t < 64) {
            double zq = (double)zrow[t] * (double)zrow[t]
                      + (double)zrow[t + 64] * (double)zrow[t + 64];
            #pragma unroll
            for (int m = 1; m < 64; m <<= 1) zq += __shfl_xor(zq, m, 64);

            double s[5]; int ix[5];
            #pragma unroll
            for (int j = 0; j < 4; j++) {
                const int c = t + 64 * j;
                double dot = 0.0;
                #pragma unroll
                for (int p = 0; p < 8; p++) dot += dotp[c * 8 + p];
                s[j] = dot; ix[j] = sel[c];
            }
            if (t < 32) {
                const int c = 256 + t;
                double dot = 0.0;
                #pragma unroll
                for (int p = 0; p < 8; p++) dot += dotp[c * 8 + p];
                s[4] = dot; ix[4] = sel[c];
            } else { s[4] = -DBL_MAX; ix[4] = INT_MAX; }

            for (int rd = 0; rd < KK; rd++) {
                double bs = s[0]; int bn = ix[0];
                #pragma unroll
                for (int j = 1; j < 5; j++)
                    if (s[j] > bs || (s[j] == bs && ix[j] < bn)) { bs = s[j]; bn = ix[j]; }
                #pragma unroll
                for (int m = 1; m < 64; m <<= 1) {
                    double os = __shfl_xor(bs, m, 64);
                    int on = __shfl_xor(bn, m, 64);
                    if (os > bs || (os == bs && on < bn)) { bs = os; bn = on; }
                }
                #pragma unroll
                for (int j = 0; j < 5; j++) if (ix[j] == bn) s[j] = -DBL_MAX;  // pop all dups
                if (t == 0) { sval[rd] = bs; sidx[rd] = bn; }
            }
            if (t == 0) dotp[0] = zq;
        }
        __syncthreads();

        if (t < KK) {
            const double zq = dotp[0];
            const int n = sidx[t];
            const int o = row * KK + t;
            out[O_VC + o] = (float)(sval[t] / sqrt(zq));
            out[O_IC + o] = (float)n;
            out[O_LR + o] = rotB[n];
        }
    } else {
        // ---- euc: bit-exact numpy-fp32 emulation (verified R3/R5/R6) ----
        sv[t] = np_euc_score(sel[t], Bk, zrow);
        if (t < 32) sv[256 + t] = np_euc_score(sel[256 + t], Bk, zrow);
        __syncthreads();

        if (t < 64) {
            float s[5]; int ix[5];
            #pragma unroll
            for (int j = 0; j < 4; j++) { s[j] = sv[t + 64 * j]; ix[j] = sel[t + 64 * j]; }
            if (t < 32) { s[4] = sv[256 + t]; ix[4] = sel[256 + t]; }
            else        { s[4] = -FLT_MAX; ix[4] = INT_MAX; }

            for (int rd = 0; rd < KK; rd++) {
                float bs = s[0]; int bn = ix[0];
                #pragma unroll
                for (int j = 1; j < 5; j++)
                    if (s[j] > bs || (s[j] == bs && ix[j] < bn)) { bs = s[j]; bn = ix[j]; }
                #pragma unroll
                for (int m = 1; m < 64; m <<= 1) {
                    float os = __shfl_xor(bs, m, 64);
                    int on = __shfl_xor(bn, m, 64);
                    if (os > bs || (os == bs && on < bn)) { bs = os; bn = on; }
                }
                #pragma unroll
                for (int j = 0; j < 5; j++) if (ix[j] == bn) s[j] = -FLT_MAX;
                if (t == 0) {
                    const int o = row * KK + rd;
                    out[O_VE + o] = bs;
                    out[O_IE + o] = (float)bn;
                    const int o3 = O_LT + o * 3;
                    out[o3 + 0] = transB[bn * 3 + 0];
                    out[o3 + 1] = transB[bn * 3 + 1];
                    out[o3 + 2] = transB[bn * 3 + 2];
                }
            }
        }
    }
}

// ---------------- launch ------------------------------------------------------------
extern "C" void kernel_launch(void* const* d_in, const int* in_sizes, int n_in,
                              void* d_out, int out_size, void* d_ws, size_t ws_size,
                              hipStream_t stream) {
    const float* zR = (const float*)d_in[0];
    const float* zT = (const float*)d_in[1];
    const float* bR = (const float*)d_in[2];
    const float* bT = (const float*)d_in[3];
    const float* rotB = (const float*)d_in[4];
    const float* transB = (const float*)d_in[5];
    float* out = (float*)d_out;

    char* ws = (char*)d_ws;
    unsigned int* Bbf = (unsigned int*)(ws + WS_BBF);
    unsigned int* bq2 = (unsigned int*)(ws + WS_BQ2);
    unsigned int* candU32 = (unsigned int*)(ws + WS_CAND);

    // 2*NPAD*16 uint4 chunks / 256 = 6336 blocks
    k_cvt<<<6336, 256, 0, stream>>>(bR, bT, (uint4*)Bbf);
    // NPAD*32 / 256 = 6336 blocks
    k_bq<<<6336, 256, 0, stream>>>(bT, bq2);
    k1_sel<<<dim3(NSLICE, 64, 2), 64, 0, stream>>>(zR, zT, Bbf, bq2, candU32);
    k2_final<<<dim3(BB, 2), 256, 0, stream>>>(zR, zT, bR, bT, rotB, transB, candU32, out);
}